// Round 3
// baseline (965.487 us; speedup 1.0000x reference)
//
#include <hip/hip_runtime.h>

// DockBoardAttention: B=65536, NDOCK=3, DCELL=25, C=32, HW=64, HD=16
// One wave64 per batch, lane = spatial position. No barriers, ~1.2KB LDS/wave.
//
// Algebra: sc[n][s] = sum_c A[n][c] g[c][s],  A = k*(dock@Wq^T + bq)@Wk  (q.bk cancels)
//          out[n][e] = sum_c U[e][c] z[n][c] + c0[e],  z[n][c] = sum_s attn[n][s] g[c][s]
//          U = Wo@Wv, c0 = Wo@bv + bo  (uses sum_s attn = 1)
// k = 0.25*log2(e) folded into A; softmax computed shift-free (|sc| << 126).
// z-pass re-reads g row-wise from global (L2-hot) instead of an LDS transpose.

#define NW 4

// ws layout (floats): M[25*32] @0, bkt[32] @800, U[16*32] @832, c0[16] @1344
__global__ void precompute_kernel(const float* __restrict__ Wq, const float* __restrict__ bq,
                                  const float* __restrict__ Wk, const float* __restrict__ Wv,
                                  const float* __restrict__ bv, const float* __restrict__ Wo,
                                  const float* __restrict__ bo, float* __restrict__ ws)
{
    const float K = 0.25f * 1.44269504088896f;
    const int t = threadIdx.x;
    for (int i = t; i < 800; i += 256) {            // M~[j][c] = K*sum_d Wq[d][j]*Wk[d][c]
        int j = i >> 5, c = i & 31;
        float s = 0.f;
        #pragma unroll
        for (int d = 0; d < 16; ++d) s += Wq[d * 25 + j] * Wk[d * 32 + c];
        ws[i] = s * K;
    }
    if (t < 32) {                                   // bkt~[c] = K*sum_d bq[d]*Wk[d][c]
        float s = 0.f;
        #pragma unroll
        for (int d = 0; d < 16; ++d) s += bq[d] * Wk[d * 32 + t];
        ws[800 + t] = s * K;
    }
    for (int i = t; i < 512; i += 256) {            // U[e][c] = sum_d Wo[e][d]*Wv[d][c]
        int e = i >> 5, c = i & 31;
        float s = 0.f;
        #pragma unroll
        for (int d = 0; d < 16; ++d) s += Wo[e * 16 + d] * Wv[d * 32 + c];
        ws[832 + i] = s;
    }
    if (t < 16) {                                   // c0[e] = sum_d Wo[e][d]*bv[d] + bo[e]
        float s = bo[t];
        #pragma unroll
        for (int d = 0; d < 16; ++d) s += Wo[t * 16 + d] * bv[d];
        ws[1344 + t] = s;
    }
}

__device__ __forceinline__ float rl(float v, int srclane) {
    return __int_as_float(__builtin_amdgcn_readlane(__float_as_int(v), srclane));
}

__global__ __launch_bounds__(256, 8) void dock_attn_kernel(
    const float* __restrict__ dock,   // [B,3,25]
    const float* __restrict__ grid,   // [B,32,64]
    const float* __restrict__ ws,     // precomputed M,bkt,U,c0
    float* __restrict__ out,          // [B,48]
    int b_total)
{
    // AZ: A rows then (reused) z rows, stride 36 words -> conflict-free reads.
    __shared__ __align__(16) float AZ[NW][112];
    __shared__ __align__(16) float attnL[NW][192];  // 3 rows of 64

    const int tid = threadIdx.x;
    const int w = tid >> 6, lane = tid & 63;
    const int b = blockIdx.x * NW + w;
    if (b >= b_total) return;          // never taken (B%4==0); no barriers, so safe

    const float* Mg  = ws;
    const float* bkt = ws + 800;
    const float* Ug  = ws + 832;
    const float* c0  = ws + 1344;

    // ---- coalesced column load of g + dock broadcast regs ----
    const float* gp = grid + (size_t)b * 2048 + lane;
    float g[32];
    #pragma unroll
    for (int c = 0; c < 32; ++c) g[c] = gp[c * 64];
    float d0 = dock[(size_t)b * 75 + lane];                           // dock 0..63
    float d1 = (lane < 11) ? dock[(size_t)b * 75 + 64 + lane] : 0.f;  // dock 64..74

    // ---- A[n][c] on lanes 0..31 (c = lane); dock via readlane ----
    if (lane < 32) {
        float bi = bkt[lane];
        float a0 = bi, a1 = bi, a2 = bi;
        #pragma unroll
        for (int j = 0; j < 25; ++j) {
            float m = Mg[j * 32 + lane];           // coalesced, L1-hot
            float q0 = rl(d0, j);
            float q1 = rl(d0, 25 + j);
            float q2 = (j < 14) ? rl(d0, 50 + j) : rl(d1, j - 14);
            a0 = fmaf(q0, m, a0);
            a1 = fmaf(q1, m, a1);
            a2 = fmaf(q2, m, a2);
        }
        AZ[w][lane] = a0; AZ[w][36 + lane] = a1; AZ[w][72 + lane] = a2;
    }

    // ---- scores: sc[n] = sum_c A[n][c]*g[c] (broadcast float4 LDS reads) ----
    float sc0 = 0.f, sc1 = 0.f, sc2 = 0.f;
    {
        const float4* A0 = (const float4*)&AZ[w][0];
        const float4* A1 = (const float4*)&AZ[w][36];
        const float4* A2 = (const float4*)&AZ[w][72];
        #pragma unroll
        for (int q = 0; q < 8; ++q) {
            float4 a = A0[q], bb = A1[q], cc = A2[q];
            float g0 = g[4 * q], g1 = g[4 * q + 1], g2 = g[4 * q + 2], g3 = g[4 * q + 3];
            sc0 = fmaf(a.x, g0, fmaf(a.y, g1, fmaf(a.z, g2, fmaf(a.w, g3, sc0))));
            sc1 = fmaf(bb.x, g0, fmaf(bb.y, g1, fmaf(bb.z, g2, fmaf(bb.w, g3, sc1))));
            sc2 = fmaf(cc.x, g0, fmaf(cc.y, g1, fmaf(cc.z, g2, fmaf(cc.w, g3, sc2))));
        }
    }

    // ---- shift-free softmax: exp2 (K folded), 64-lane sum, rcp-normalize ----
    float at0 = __builtin_amdgcn_exp2f(sc0);
    float at1 = __builtin_amdgcn_exp2f(sc1);
    float at2 = __builtin_amdgcn_exp2f(sc2);
    {
        float s0 = at0, s1 = at1, s2 = at2;
        #pragma unroll
        for (int off = 1; off < 64; off <<= 1) {
            s0 += __shfl_xor(s0, off);
            s1 += __shfl_xor(s1, off);
            s2 += __shfl_xor(s2, off);
        }
        at0 *= __builtin_amdgcn_rcpf(s0);
        at1 *= __builtin_amdgcn_rcpf(s1);
        at2 *= __builtin_amdgcn_rcpf(s2);
    }
    attnL[w][lane] = at0; attnL[w][64 + lane] = at1; attnL[w][128 + lane] = at2;

    // ---- z[n][c] = sum_s attn[n][s]*g[c][s]; g re-read row-wise (L2-hot) ----
    {   // pass 1: n = lane>>5 in {0,1}, c = lane&31  (n=0/1 lanes share addresses)
        const int n = lane >> 5, c = lane & 31;
        const float4* gr = (const float4*)(grid + (size_t)b * 2048 + c * 64);
        const float4* ar = (const float4*)&attnL[w][n * 64];
        float zx = 0.f, zy = 0.f, zz = 0.f, zw = 0.f;
        #pragma unroll
        for (int j = 0; j < 16; ++j) {
            float4 gg = gr[j], aa = ar[j];
            zx = fmaf(aa.x, gg.x, zx);
            zy = fmaf(aa.y, gg.y, zy);
            zz = fmaf(aa.z, gg.z, zz);
            zw = fmaf(aa.w, gg.w, zw);
        }
        AZ[w][n * 36 + c] = (zx + zy) + (zz + zw);   // overwrites dead A rows
    }
    if (lane < 32) {   // pass 2: n = 2, c = lane
        const float4* gr = (const float4*)(grid + (size_t)b * 2048 + lane * 64);
        const float4* ar = (const float4*)&attnL[w][128];
        float zx = 0.f, zy = 0.f, zz = 0.f, zw = 0.f;
        #pragma unroll
        for (int j = 0; j < 16; ++j) {
            float4 gg = gr[j], aa = ar[j];
            zx = fmaf(aa.x, gg.x, zx);
            zy = fmaf(aa.y, gg.y, zy);
            zz = fmaf(aa.z, gg.z, zz);
            zw = fmaf(aa.w, gg.w, zw);
        }
        AZ[w][72 + lane] = (zx + zy) + (zz + zw);
    }

    // ---- out[n][e] = sum_c U[e][c]*z[n][c] + c0[e]  (lanes 0..47) ----
    if (lane < 48) {
        const int n = lane >> 4, e = lane & 15;
        const float4* Ur = (const float4*)(Ug + e * 32);
        const float4* zr = (const float4*)&AZ[w][n * 36];
        float acc0 = c0[e], acc1 = 0.f, acc2 = 0.f, acc3 = 0.f;
        #pragma unroll
        for (int q = 0; q < 8; ++q) {
            float4 u = Ur[q], z = zr[q];
            acc0 = fmaf(u.x, z.x, acc0);
            acc1 = fmaf(u.y, z.y, acc1);
            acc2 = fmaf(u.z, z.z, acc2);
            acc3 = fmaf(u.w, z.w, acc3);
        }
        out[(size_t)b * 48 + lane] = (acc0 + acc1) + (acc2 + acc3);
    }
}

extern "C" void kernel_launch(void* const* d_in, const int* in_sizes, int n_in,
                              void* d_out, int out_size, void* d_ws, size_t ws_size,
                              hipStream_t stream) {
    const float* dock = (const float*)d_in[0];
    const float* grid = (const float*)d_in[1];
    const float* Wq   = (const float*)d_in[2];
    const float* bq   = (const float*)d_in[3];
    const float* Wk   = (const float*)d_in[4];
    // d_in[5] = bk: constant over spatial axis -> cancels in softmax; unused
    const float* Wv   = (const float*)d_in[6];
    const float* bv   = (const float*)d_in[7];
    const float* Wo   = (const float*)d_in[8];
    const float* bo   = (const float*)d_in[9];
    float* out = (float*)d_out;
    float* ws  = (float*)d_ws;

    precompute_kernel<<<1, 256, 0, stream>>>(Wq, bq, Wk, Wv, bv, Wo, bo, ws);

    const int b_total = in_sizes[0] / 75;   // 65536
    const int blocks = (b_total + NW - 1) / NW;
    dock_attn_kernel<<<blocks, 256, 0, stream>>>(dock, grid, ws, out, b_total);
}

// Round 4
// 714.297 us; speedup vs baseline: 1.3517x; 1.3517x over previous
//
#include <hip/hip_runtime.h>

// DockBoardAttention: B=65536, NDOCK=3, DCELL=25, C=32, HW=64, HD=16
// One wave64 per batch, lane = spatial position. No barriers; all LDS wave-private
// (in-order per-wave DS pipe + compiler lgkmcnt waits make this safe).
//
// Algebra: sc[n][s] = sum_c A[n][c] g[c][s],  A = k*(dock@Wq^T + bq)@Wk  (q.bk cancels)
//          out[n][e] = sum_c U[e][c] z[n][c] + c0[e],  z[n][c] = sum_s attn[n][s] g[c][s]
//          U = Wo@Wv, c0 = Wo@bv + bo  (uses sum_s attn = 1)
// k = 0.25*log2(e) folded into A; softmax shift-free (|sc| << 126).
// z-pass uses an LDS transpose of g, chunked 16 channels at a time so LDS stays
// at 21.1 KB/block -> 7 blocks/CU = 28 waves (round-2's 40 KB capped at 16).

#define NW 4
#define GTS 66   // gT/attnL row stride (words): conflict-free float2 row reads

// ws layout (floats): M[25*32] @0, bkt[32] @800, U[16*32] @832, c0[16] @1344
__global__ void precompute_kernel(const float* __restrict__ Wq, const float* __restrict__ bq,
                                  const float* __restrict__ Wk, const float* __restrict__ Wv,
                                  const float* __restrict__ bv, const float* __restrict__ Wo,
                                  const float* __restrict__ bo, float* __restrict__ ws)
{
    const float K = 0.25f * 1.44269504088896f;
    const int t = threadIdx.x;
    for (int i = t; i < 800; i += 256) {            // M~[j][c] = K*sum_d Wq[d][j]*Wk[d][c]
        int j = i >> 5, c = i & 31;
        float s = 0.f;
        #pragma unroll
        for (int d = 0; d < 16; ++d) s += Wq[d * 25 + j] * Wk[d * 32 + c];
        ws[i] = s * K;
    }
    if (t < 32) {                                   // bkt~[c] = K*sum_d bq[d]*Wk[d][c]
        float s = 0.f;
        #pragma unroll
        for (int d = 0; d < 16; ++d) s += bq[d] * Wk[d * 32 + t];
        ws[800 + t] = s * K;
    }
    for (int i = t; i < 512; i += 256) {            // U[e][c] = sum_d Wo[e][d]*Wv[d][c]
        int e = i >> 5, c = i & 31;
        float s = 0.f;
        #pragma unroll
        for (int d = 0; d < 16; ++d) s += Wo[e * 16 + d] * Wv[d * 32 + c];
        ws[832 + i] = s;
    }
    if (t < 16) {                                   // c0[e] = sum_d Wo[e][d]*bv[d] + bo[e]
        float s = bo[t];
        #pragma unroll
        for (int d = 0; d < 16; ++d) s += Wo[t * 16 + d] * bv[d];
        ws[1344 + t] = s;
    }
}

__device__ __forceinline__ float rl(float v, int srclane) {
    return __int_as_float(__builtin_amdgcn_readlane(__float_as_int(v), srclane));
}

__global__ __launch_bounds__(256, 7) void dock_attn_kernel(
    const float* __restrict__ dock,   // [B,3,25]
    const float* __restrict__ grid,   // [B,32,64]
    const float* __restrict__ ws,     // precomputed M,bkt,U,c0
    float* __restrict__ out,          // [B,48]
    int b_total)
{
    __shared__ __align__(16) float AZ[NW][96];        // A rows then z rows, stride 32
    __shared__ __align__(16) float attnL[NW][200];    // 3 rows, stride 66
    __shared__ __align__(16) float gT[NW][16 * GTS];  // one 16-channel transpose chunk

    const int tid = threadIdx.x;
    const int w = tid >> 6, lane = tid & 63;
    const int b = blockIdx.x * NW + w;
    if (b >= b_total) return;          // never taken (B%4==0); no barriers, so safe

    const float* Mg  = ws;
    const float* bkt = ws + 800;
    const float* Ug  = ws + 832;
    const float* c0  = ws + 1344;

    // ---- coalesced column load of g + dock broadcast regs ----
    const float* gp = grid + (size_t)b * 2048 + lane;
    float g[32];
    #pragma unroll
    for (int c = 0; c < 32; ++c) g[c] = gp[c * 64];
    float d0 = dock[(size_t)b * 75 + lane];                           // dock 0..63
    float d1 = (lane < 11) ? dock[(size_t)b * 75 + 64 + lane] : 0.f;  // dock 64..74

    // ---- A[n][c] on lanes 0..31 (c = lane); dock via readlane (imm lanes) ----
    if (lane < 32) {
        float bi = bkt[lane];
        float a0 = bi, a1 = bi, a2 = bi;
        #pragma unroll
        for (int j = 0; j < 25; ++j) {
            float m = Mg[j * 32 + lane];           // coalesced, L1-hot
            float q0 = rl(d0, j);
            float q1 = rl(d0, 25 + j);
            float q2 = (j < 14) ? rl(d0, 50 + j) : rl(d1, j - 14);
            a0 = fmaf(q0, m, a0);
            a1 = fmaf(q1, m, a1);
            a2 = fmaf(q2, m, a2);
        }
        AZ[w][lane] = a0; AZ[w][32 + lane] = a1; AZ[w][64 + lane] = a2;
    }

    // ---- scores: sc[n] = sum_c A[n][c]*g[c] (broadcast float4 LDS reads) ----
    float sc0 = 0.f, sc1 = 0.f, sc2 = 0.f;
    {
        const float4* A0 = (const float4*)&AZ[w][0];
        const float4* A1 = (const float4*)&AZ[w][32];
        const float4* A2 = (const float4*)&AZ[w][64];
        #pragma unroll
        for (int q = 0; q < 8; ++q) {
            float4 a = A0[q], bb = A1[q], cc = A2[q];
            float g0 = g[4 * q], g1 = g[4 * q + 1], g2 = g[4 * q + 2], g3 = g[4 * q + 3];
            sc0 = fmaf(a.x, g0, fmaf(a.y, g1, fmaf(a.z, g2, fmaf(a.w, g3, sc0))));
            sc1 = fmaf(bb.x, g0, fmaf(bb.y, g1, fmaf(bb.z, g2, fmaf(bb.w, g3, sc1))));
            sc2 = fmaf(cc.x, g0, fmaf(cc.y, g1, fmaf(cc.z, g2, fmaf(cc.w, g3, sc2))));
        }
    }

    // ---- chunk-0 transpose writes (overlap with softmax butterfly below) ----
    #pragma unroll
    for (int c = 0; c < 16; ++c) gT[w][c * GTS + lane] = g[c];

    // ---- shift-free softmax: exp2 (K folded), 64-lane sum, rcp-normalize ----
    float at0 = __builtin_amdgcn_exp2f(sc0);
    float at1 = __builtin_amdgcn_exp2f(sc1);
    float at2 = __builtin_amdgcn_exp2f(sc2);
    {
        float s0 = at0, s1 = at1, s2 = at2;
        #pragma unroll
        for (int off = 1; off < 64; off <<= 1) {
            s0 += __shfl_xor(s0, off);
            s1 += __shfl_xor(s1, off);
            s2 += __shfl_xor(s2, off);
        }
        at0 *= __builtin_amdgcn_rcpf(s0);
        at1 *= __builtin_amdgcn_rcpf(s1);
        at2 *= __builtin_amdgcn_rcpf(s2);
    }
    attnL[w][lane] = at0; attnL[w][66 + lane] = at1; attnL[w][132 + lane] = at2;

    // ---- z chunk 0: lanes 0..47 -> (n = lane>>4, c = lane&15) ----
    if (lane < 48) {
        const int n = lane >> 4, cl = lane & 15;
        const float2* ar = (const float2*)&attnL[w][n * 66];
        const float2* gr = (const float2*)&gT[w][cl * GTS];
        float zx = 0.f, zy = 0.f;
        #pragma unroll
        for (int j = 0; j < 32; ++j) {
            float2 a = ar[j], gg = gr[j];
            zx = fmaf(a.x, gg.x, zx);
            zy = fmaf(a.y, gg.y, zy);
        }
        AZ[w][n * 32 + cl] = zx + zy;      // overwrites dead A rows
    }

    // ---- chunk-1 transpose (in-order DS pipe: safe after chunk-0 reads) ----
    #pragma unroll
    for (int c = 16; c < 32; ++c) gT[w][(c - 16) * GTS + lane] = g[c];

    // ---- z chunk 1: same lanes, c = 16 + (lane&15) ----
    if (lane < 48) {
        const int n = lane >> 4, cl = lane & 15;
        const float2* ar = (const float2*)&attnL[w][n * 66];
        const float2* gr = (const float2*)&gT[w][cl * GTS];
        float zx = 0.f, zy = 0.f;
        #pragma unroll
        for (int j = 0; j < 32; ++j) {
            float2 a = ar[j], gg = gr[j];
            zx = fmaf(a.x, gg.x, zx);
            zy = fmaf(a.y, gg.y, zy);
        }
        AZ[w][n * 32 + 16 + cl] = zx + zy;
    }

    // ---- out[n][e] = sum_c U[e][c]*z[n][c] + c0[e]  (lanes 0..47) ----
    if (lane < 48) {
        const int n = lane >> 4, e = lane & 15;
        const float4* Ur = (const float4*)(Ug + e * 32);
        const float4* zr = (const float4*)&AZ[w][n * 32];
        float acc0 = c0[e], acc1 = 0.f, acc2 = 0.f, acc3 = 0.f;
        #pragma unroll
        for (int q = 0; q < 8; ++q) {
            float4 u = Ur[q], z = zr[q];
            acc0 = fmaf(u.x, z.x, acc0);
            acc1 = fmaf(u.y, z.y, acc1);
            acc2 = fmaf(u.z, z.z, acc2);
            acc3 = fmaf(u.w, z.w, acc3);
        }
        out[(size_t)b * 48 + lane] = (acc0 + acc1) + (acc2 + acc3);
    }
}

extern "C" void kernel_launch(void* const* d_in, const int* in_sizes, int n_in,
                              void* d_out, int out_size, void* d_ws, size_t ws_size,
                              hipStream_t stream) {
    const float* dock = (const float*)d_in[0];
    const float* grid = (const float*)d_in[1];
    const float* Wq   = (const float*)d_in[2];
    const float* bq   = (const float*)d_in[3];
    const float* Wk   = (const float*)d_in[4];
    // d_in[5] = bk: constant over spatial axis -> cancels in softmax; unused
    const float* Wv   = (const float*)d_in[6];
    const float* bv   = (const float*)d_in[7];
    const float* Wo   = (const float*)d_in[8];
    const float* bo   = (const float*)d_in[9];
    float* out = (float*)d_out;
    float* ws  = (float*)d_ws;

    precompute_kernel<<<1, 256, 0, stream>>>(Wq, bq, Wk, Wv, bv, Wo, bo, ws);

    const int b_total = in_sizes[0] / 75;   // 65536
    const int blocks = (b_total + NW - 1) / NW;
    dock_attn_kernel<<<blocks, 256, 0, stream>>>(dock, grid, ws, out, b_total);
}